// Round 1
// baseline (247.779 us; speedup 1.0000x reference)
//
#include <hip/hip_runtime.h>

#define NDRUG 846
#define EDIM 256
#define NS 128

typedef short s8v __attribute__((ext_vector_type(8)));
typedef __bf16 b8v __attribute__((ext_vector_type(8)));
typedef float f32x4 __attribute__((ext_vector_type(4)));

// round-to-nearest-even f32 -> bf16 bits
static __device__ __forceinline__ unsigned short f2bf(float f) {
  union { float f; unsigned u; } v; v.f = f;
  unsigned r = v.u + 0x7fffu + ((v.u >> 16) & 1u);
  return (unsigned short)(r >> 16);
}

// SFINAE hedge: gfx950 builtin may take short8 or __bf16x8 depending on ROCm.
template <typename V>
static __device__ __forceinline__ auto mfma_impl(V a, V b, f32x4 c, int)
    -> decltype(__builtin_amdgcn_mfma_f32_16x16x32_bf16(a, b, c, 0, 0, 0)) {
  return __builtin_amdgcn_mfma_f32_16x16x32_bf16(a, b, c, 0, 0, 0);
}
template <typename V>
static __device__ __forceinline__ f32x4 mfma_impl(V a, V b, f32x4 c, long) {
  b8v ab = __builtin_bit_cast(b8v, a);
  b8v bb = __builtin_bit_cast(b8v, b);
  return __builtin_amdgcn_mfma_f32_16x16x32_bf16(ab, bb, c, 0, 0, 0);
}
static __device__ __forceinline__ f32x4 mfma16(s8v a, s8v b, f32x4 c) {
  return mfma_impl(a, b, c, 0);
}

// Per-drug GEMM: C[128 rows][32 cols owned by wave w] = A(LDS bf16) @ W(global f32)
// A-frag: row = lane&15 (swizzled LDS), k = 32*kk + 8*(lane>>4) + j
// B-frag: col = lane&15 within 16-col tile,  same k mapping (consistency => correct)
static __device__ __forceinline__ void gemm_tile(const float* __restrict__ Wp,
                                                 const unsigned short* s_ab,
                                                 int w, int g, int lr,
                                                 f32x4 acc[8][2]) {
#pragma unroll
  for (int mt = 0; mt < 8; ++mt) {
    acc[mt][0] = (f32x4){0.f, 0.f, 0.f, 0.f};
    acc[mt][1] = (f32x4){0.f, 0.f, 0.f, 0.f};
  }
  const int col0 = 32 * w + lr;
  const int swz = (lr & 7) << 4;
#pragma unroll
  for (int kk = 0; kk < 8; ++kk) {
    const float* p0 = Wp + (32 * kk + 8 * g) * EDIM + col0;
    s8v bf0, bf1;
#pragma unroll
    for (int j = 0; j < 8; ++j) {
      bf0[j] = (short)f2bf(p0[j * EDIM]);
      bf1[j] = (short)f2bf(p0[j * EDIM + 16]);
    }
    const int kb = (32 * kk + 8 * g) * 2;
#pragma unroll
    for (int mt = 0; mt < 8; ++mt) {
      const int row = 16 * mt + lr;
      s8v af = *(const s8v*)((const char*)s_ab + ((row * 512 + kb) ^ swz));
      acc[mt][0] = mfma16(af, bf0, acc[mt][0]);
      acc[mt][1] = mfma16(af, bf1, acc[mt][1]);
    }
  }
}

__global__ __launch_bounds__(512) void gnn_main(
    const int* __restrict__ drug_name,
    const int* __restrict__ adj_tail,
    const int* __restrict__ adj_relation,
    const float* __restrict__ drug_table,
    const float* __restrict__ rela_table,
    const float* __restrict__ ent_table,
    const float* __restrict__ W1,
    const float* __restrict__ b1,
    const float* __restrict__ W2,
    const float* __restrict__ b2,
    const float* __restrict__ lin_w,
    const float* __restrict__ lin_b,
    float* __restrict__ xT) {
  __shared__ unsigned short s_ab[NS * EDIM];  // 64KB, XOR-swizzled bf16 tile
  __shared__ float s_d[EDIM];
  __shared__ int s_tail[NS];
  __shared__ float s_scorep[8][NS];
  __shared__ float s_attn[NS];
  __shared__ float s_we[2][EDIM];
  __shared__ float s_lin[2][EDIM];

  const int b = blockIdx.x;
  const int tid = threadIdx.x;
  const int w = tid >> 6;
  const int l = tid & 63;
  const int g = l >> 4;
  const int lr = l & 15;

  if (tid < EDIM) {
    const int dn = drug_name[b];
    s_d[tid] = drug_table[(long)dn * EDIM + tid];
  } else if (tid < EDIM + NS) {
    s_tail[tid - EDIM] = adj_tail[b * NS + (tid - EDIM)];
  }
  __syncthreads();

  // dr[n][e] = d[e] * r[n][e] -> LDS bf16 (swizzled)
  {
    const int n = tid >> 2;
    const int e0 = (tid & 3) * 64;
    const int rel = adj_relation[b * NS + n];
    const float* rrow = rela_table + (long)rel * EDIM;
    const int swz = (n & 7) << 4;
#pragma unroll
    for (int c = 0; c < 8; ++c) {
      const int e = e0 + c * 8;
      float4 p0 = *(const float4*)(rrow + e);
      float4 p1 = *(const float4*)(rrow + e + 4);
      s8v v;
      v[0] = (short)f2bf(p0.x * s_d[e + 0]);
      v[1] = (short)f2bf(p0.y * s_d[e + 1]);
      v[2] = (short)f2bf(p0.z * s_d[e + 2]);
      v[3] = (short)f2bf(p0.w * s_d[e + 3]);
      v[4] = (short)f2bf(p1.x * s_d[e + 4]);
      v[5] = (short)f2bf(p1.y * s_d[e + 5]);
      v[6] = (short)f2bf(p1.z * s_d[e + 6]);
      v[7] = (short)f2bf(p1.w * s_d[e + 7]);
      *(s8v*)((char*)s_ab + ((n * 512 + e * 2) ^ swz)) = v;
    }
  }
  __syncthreads();

  f32x4 acc[8][2];
  // h1 = dr @ W1[b]
  gemm_tile(W1 + (long)b * EDIM * EDIM, s_ab, w, g, lr, acc);
  __syncthreads();  // all waves done reading dr

  // h1 += b1; relu; write back into s_ab (bf16, swizzled). Disjoint col slabs per wave.
#pragma unroll
  for (int mt = 0; mt < 8; ++mt) {
#pragma unroll
    for (int jj = 0; jj < 4; ++jj) {
      const int n = 16 * mt + 4 * g + jj;
      const int swz = (n & 7) << 4;
#pragma unroll
      for (int nt = 0; nt < 2; ++nt) {
        const int f = 32 * w + 16 * nt + lr;
        float v = acc[mt][nt][jj] + b1[n * EDIM + f];
        v = fmaxf(v, 0.f);
        *(unsigned short*)((char*)s_ab + ((n * 512 + f * 2) ^ swz)) = f2bf(v);
      }
    }
  }
  __syncthreads();

  // h2 = h1 @ W2[b]
  gemm_tile(W2 + (long)b * EDIM * EDIM, s_ab, w, g, lr, acc);

  // score[n] = sum_f (h2[n][f] + b2[n][f]); per-wave 32-col partials, 16-lane reduce
#pragma unroll
  for (int mt = 0; mt < 8; ++mt) {
#pragma unroll
    for (int jj = 0; jj < 4; ++jj) {
      const int n = 16 * mt + 4 * g + jj;
      const int f = 32 * w + lr;
      float v = acc[mt][0][jj] + acc[mt][1][jj] + b2[n * EDIM + f] + b2[n * EDIM + f + 16];
#pragma unroll
      for (int off = 1; off < 16; off <<= 1) v += __shfl_xor(v, off);
      if (lr == 0) s_scorep[w][n] = v;
    }
  }
  __syncthreads();

  // softmax over 128 neighbors (wave 0), deterministic 8-term sums
  if (w == 0) {
    float v0 = 0.f, v1 = 0.f;
#pragma unroll
    for (int ww = 0; ww < 8; ++ww) {
      v0 += s_scorep[ww][l];
      v1 += s_scorep[ww][l + 64];
    }
    float m = fmaxf(v0, v1);
#pragma unroll
    for (int off = 1; off < 64; off <<= 1) m = fmaxf(m, __shfl_xor(m, off));
    const float e0 = expf(v0 - m), e1 = expf(v1 - m);
    float s = e0 + e1;
#pragma unroll
    for (int off = 1; off < 64; off <<= 1) s += __shfl_xor(s, off);
    const float inv = 1.f / s;
    s_attn[l] = e0 * inv;
    s_attn[l + 64] = e1 * inv;
  }
  __syncthreads();

  // weighted_ent[f] = sum_n attn[n] * ent_table[tail[n]][f]
  {
    const int f = tid & 255;
    const int half = tid >> 8;
    const int nbase = half * 64;
    float a = 0.f;
#pragma unroll 4
    for (int i = 0; i < 64; ++i) {
      const int n = nbase + i;
      a += s_attn[n] * ent_table[(long)s_tail[n] * EDIM + f];
    }
    s_we[half][f] = a;
  }
  __syncthreads();

  // x = [we | d] @ lin_w  (split the 512-row contraction across the two halves)
  {
    const int f = tid & 255;
    const int half = tid >> 8;
    const float* wp = lin_w + (long)half * EDIM * EDIM + f;
    float a = 0.f;
    if (half == 0) {
      for (int e = 0; e < EDIM; ++e) a += (s_we[0][e] + s_we[1][e]) * wp[(long)e * EDIM];
    } else {
      for (int e = 0; e < EDIM; ++e) a += s_d[e] * wp[(long)e * EDIM];
    }
    s_lin[half][f] = a;
  }
  __syncthreads();

  if (tid < EDIM) {
    float x = s_lin[0][tid] + s_lin[1][tid] + lin_b[tid];
    x = fmaxf(x, 0.f);
    xT[tid * NDRUG + b] = x;  // transposed for coalesced BN reads
  }
}

__global__ __launch_bounds__(256) void bn_kernel(const float* __restrict__ xT,
                                                 const float* __restrict__ gamma,
                                                 const float* __restrict__ beta,
                                                 float* __restrict__ out) {
  const int f = blockIdx.x;
  const int t = threadIdx.x;
  const float* col = xT + f * NDRUG;
  float s = 0.f, ss = 0.f;
  for (int i = t; i < NDRUG; i += 256) {
    const float v = col[i];
    s += v;
    ss += v * v;
  }
#pragma unroll
  for (int off = 1; off < 64; off <<= 1) {
    s += __shfl_xor(s, off);
    ss += __shfl_xor(ss, off);
  }
  __shared__ float as_[4], ass_[4];
  if ((t & 63) == 0) {
    as_[t >> 6] = s;
    ass_[t >> 6] = ss;
  }
  __syncthreads();
  s = as_[0] + as_[1] + as_[2] + as_[3];
  ss = ass_[0] + ass_[1] + ass_[2] + ass_[3];
  const float mean = s * (1.f / NDRUG);
  const float var = ss * (1.f / NDRUG) - mean * mean;  // biased batch variance
  const float sc = rsqrtf(var + 1e-5f) * gamma[f];
  const float sh = beta[f] - mean * sc;
  for (int i = t; i < NDRUG; i += 256) out[i * EDIM + f] = col[i] * sc + sh;
}

__global__ void tail_kernel(const float* __restrict__ gnn1, const int* __restrict__ idx,
                            float* __restrict__ out) {
  const int total4 = NDRUG * EDIM / 4;
  const float4* s4 = (const float4*)gnn1;
  float4* d4 = (float4*)(out + NDRUG * EDIM);
  for (int i = blockIdx.x * blockDim.x + threadIdx.x; i < total4;
       i += gridDim.x * blockDim.x)
    d4[i] = s4[i];
  if (blockIdx.x == 0 && threadIdx.x == 0) out[2 * NDRUG * EDIM] = (float)idx[0];
}

extern "C" void kernel_launch(void* const* d_in, const int* in_sizes, int n_in,
                              void* d_out, int out_size, void* d_ws, size_t ws_size,
                              hipStream_t stream) {
  const float* gnn1       = (const float*)d_in[0];
  const int*   idx        = (const int*)d_in[1];
  const int*   drug_name  = (const int*)d_in[2];
  const int*   adj_tail   = (const int*)d_in[3];
  const int*   adj_rel    = (const int*)d_in[4];
  const float* drug_table = (const float*)d_in[5];
  const float* rela_table = (const float*)d_in[6];
  const float* ent_table  = (const float*)d_in[7];
  const float* W1         = (const float*)d_in[8];
  const float* b1         = (const float*)d_in[9];
  const float* W2         = (const float*)d_in[10];
  const float* b2         = (const float*)d_in[11];
  const float* lin_w      = (const float*)d_in[12];
  const float* lin_b      = (const float*)d_in[13];
  const float* bn_g       = (const float*)d_in[14];
  const float* bn_b       = (const float*)d_in[15];

  float* out = (float*)d_out;
  float* xT  = (float*)d_ws;  // [EDIM][NDRUG] f32, 866304 bytes

  gnn_main<<<NDRUG, 512, 0, stream>>>(drug_name, adj_tail, adj_rel, drug_table,
                                      rela_table, ent_table, W1, b1, W2, b2,
                                      lin_w, lin_b, xT);
  bn_kernel<<<EDIM, 256, 0, stream>>>(xT, bn_g, bn_b, out);
  tail_kernel<<<240, 256, 0, stream>>>(gnn1, idx, out);
}

// Round 2
// 166.287 us; speedup vs baseline: 1.4901x; 1.4901x over previous
//
#include <hip/hip_runtime.h>

#define NDRUG 846
#define EDIM 256
#define NS 128

typedef short s8v __attribute__((ext_vector_type(8)));
typedef __bf16 b8v __attribute__((ext_vector_type(8)));
typedef float f32x4 __attribute__((ext_vector_type(4)));

// round-to-nearest-even f32 -> bf16 bits
static __device__ __forceinline__ unsigned short f2bf(float f) {
  union { float f; unsigned u; } v; v.f = f;
  unsigned r = v.u + 0x7fffu + ((v.u >> 16) & 1u);
  return (unsigned short)(r >> 16);
}

// SFINAE hedge: gfx950 builtin may take short8 or __bf16x8 depending on ROCm.
template <typename V>
static __device__ __forceinline__ auto mfma_impl(V a, V b, f32x4 c, int)
    -> decltype(__builtin_amdgcn_mfma_f32_16x16x32_bf16(a, b, c, 0, 0, 0)) {
  return __builtin_amdgcn_mfma_f32_16x16x32_bf16(a, b, c, 0, 0, 0);
}
template <typename V>
static __device__ __forceinline__ f32x4 mfma_impl(V a, V b, f32x4 c, long) {
  b8v ab = __builtin_bit_cast(b8v, a);
  b8v bb = __builtin_bit_cast(b8v, b);
  return __builtin_amdgcn_mfma_f32_16x16x32_bf16(ab, bb, c, 0, 0, 0);
}
static __device__ __forceinline__ f32x4 mfma16(s8v a, s8v b, f32x4 c) {
  return mfma_impl(a, b, c, 0);
}

__global__ __launch_bounds__(512, 4) void gnn_main(
    const int* __restrict__ drug_name,
    const int* __restrict__ adj_tail,
    const int* __restrict__ adj_relation,
    const float* __restrict__ drug_table,
    const float* __restrict__ rela_table,
    const float* __restrict__ ent_table,
    const float* __restrict__ W1,
    const float* __restrict__ b1,
    const float* __restrict__ W2,
    const float* __restrict__ b2,
    const float* __restrict__ lin_w,
    const float* __restrict__ lin_b,
    float* __restrict__ xT) {
  __shared__ unsigned short s_ab[NS * EDIM];  // 64KB, XOR-swizzled bf16 dr tile
  __shared__ float s_d[EDIM];
  __shared__ int s_tail[NS];
  __shared__ float s_w2sum[EDIM];
  __shared__ float s_b2sum[NS];
  __shared__ float s_scorep[8][NS];
  __shared__ float s_attn[NS];
  __shared__ float s_we[2][EDIM];
  __shared__ float s_lin[2][EDIM];

  const int b = blockIdx.x;
  const int tid = threadIdx.x;
  const int w = tid >> 6;
  const int l = tid & 63;
  const int g = l >> 4;
  const int lr = l & 15;

  if (tid < EDIM) {
    const int dn = drug_name[b];
    s_d[tid] = drug_table[(long)dn * EDIM + tid];
  } else if (tid < EDIM + NS) {
    s_tail[tid - EDIM] = adj_tail[b * NS + (tid - EDIM)];
  }

  // w2sum[e] = sum_f W2[b][e][f]  (coalesced f32 row-sum; replaces all of GEMM2)
  // b2sum[n] = sum_f b2[n][f]
  {
    const int rg = tid >> 4;          // 0..31 row group
    const int lc = (tid & 15) * 16;   // 16 cols per lane
    const float* W2p = W2 + (long)b * EDIM * EDIM;
#pragma unroll
    for (int s = 0; s < 8; ++s) {
      const int e = 32 * s + rg;
      const float* p = W2p + e * EDIM + lc;
      float4 a0 = *(const float4*)p, a1 = *(const float4*)(p + 4);
      float4 a2 = *(const float4*)(p + 8), a3 = *(const float4*)(p + 12);
      float v = a0.x + a0.y + a0.z + a0.w + a1.x + a1.y + a1.z + a1.w +
                a2.x + a2.y + a2.z + a2.w + a3.x + a3.y + a3.z + a3.w;
#pragma unroll
      for (int off = 1; off < 16; off <<= 1) v += __shfl_xor(v, off);
      if ((tid & 15) == 0) s_w2sum[e] = v;
    }
#pragma unroll
    for (int s = 0; s < 4; ++s) {
      const int n = 32 * s + rg;
      const float* p = b2 + n * EDIM + lc;
      float4 a0 = *(const float4*)p, a1 = *(const float4*)(p + 4);
      float4 a2 = *(const float4*)(p + 8), a3 = *(const float4*)(p + 12);
      float v = a0.x + a0.y + a0.z + a0.w + a1.x + a1.y + a1.z + a1.w +
                a2.x + a2.y + a2.z + a2.w + a3.x + a3.y + a3.z + a3.w;
#pragma unroll
      for (int off = 1; off < 16; off <<= 1) v += __shfl_xor(v, off);
      if ((tid & 15) == 0) s_b2sum[n] = v;
    }
  }
  __syncthreads();

  // dr[n][e] = d[e] * r[n][e] -> LDS bf16 (XOR-swizzled)
  {
    const int n = tid >> 2;
    const int e0 = (tid & 3) * 64;
    const int rel = adj_relation[b * NS + n];
    const float* rrow = rela_table + (long)rel * EDIM;
    const int swz = (n & 7) << 4;
#pragma unroll
    for (int c = 0; c < 8; ++c) {
      const int e = e0 + c * 8;
      float4 p0 = *(const float4*)(rrow + e);
      float4 p1 = *(const float4*)(rrow + e + 4);
      s8v v;
      v[0] = (short)f2bf(p0.x * s_d[e + 0]);
      v[1] = (short)f2bf(p0.y * s_d[e + 1]);
      v[2] = (short)f2bf(p0.z * s_d[e + 2]);
      v[3] = (short)f2bf(p0.w * s_d[e + 3]);
      v[4] = (short)f2bf(p1.x * s_d[e + 4]);
      v[5] = (short)f2bf(p1.y * s_d[e + 5]);
      v[6] = (short)f2bf(p1.z * s_d[e + 6]);
      v[7] = (short)f2bf(p1.w * s_d[e + 7]);
      *(s8v*)((char*)s_ab + ((n * 512 + e * 2) ^ swz)) = v;
    }
  }
  __syncthreads();

  // h1 = dr @ W1[b]; wave w owns cols [32w, 32w+32).
  // B-frag via per-lane scalar loads, double-buffered: loads for kk+1 issued
  // before kk's MFMAs, converted after them (16 f32 live across MFMA block).
  f32x4 acc[8][2];
#pragma unroll
  for (int mt = 0; mt < 8; ++mt) {
    acc[mt][0] = (f32x4){0.f, 0.f, 0.f, 0.f};
    acc[mt][1] = (f32x4){0.f, 0.f, 0.f, 0.f};
  }
  {
    const float* Wp = W1 + (long)b * EDIM * EDIM;
    const int col0 = 32 * w + lr;
    const int swz = (lr & 7) << 4;
    float fb[16];
    s8v bf0[2], bf1[2];
    {
      const float* pk = Wp + (8 * g) * EDIM + col0;
#pragma unroll
      for (int j = 0; j < 8; ++j) {
        fb[j] = pk[j * EDIM];
        fb[8 + j] = pk[j * EDIM + 16];
      }
#pragma unroll
      for (int j = 0; j < 8; ++j) {
        bf0[0][j] = (short)f2bf(fb[j]);
        bf1[0][j] = (short)f2bf(fb[8 + j]);
      }
    }
#pragma unroll
    for (int kk = 0; kk < 8; ++kk) {
      const int c = kk & 1;
      if (kk < 7) {
        const float* pk = Wp + (32 * (kk + 1) + 8 * g) * EDIM + col0;
#pragma unroll
        for (int j = 0; j < 8; ++j) {
          fb[j] = pk[j * EDIM];
          fb[8 + j] = pk[j * EDIM + 16];
        }
      }
      const int kb = (32 * kk + 8 * g) * 2;
#pragma unroll
      for (int mt = 0; mt < 8; ++mt) {
        const int row = 16 * mt + lr;
        s8v af = *(const s8v*)((const char*)s_ab + ((row * 512 + kb) ^ swz));
        acc[mt][0] = mfma16(af, bf0[c], acc[mt][0]);
        acc[mt][1] = mfma16(af, bf1[c], acc[mt][1]);
      }
      if (kk < 7) {
#pragma unroll
        for (int j = 0; j < 8; ++j) {
          bf0[c ^ 1][j] = (short)f2bf(fb[j]);
          bf1[c ^ 1][j] = (short)f2bf(fb[8 + j]);
        }
      }
    }
  }

  // score[n] = sum_f relu(h1[n][f]+b1[n][f]) * w2sum[f]; per-wave partials
#pragma unroll
  for (int mt = 0; mt < 8; ++mt) {
#pragma unroll
    for (int jj = 0; jj < 4; ++jj) {
      const int n = 16 * mt + 4 * g + jj;
      const int f0 = 32 * w + lr;
      const int f1 = f0 + 16;
      float v = fmaxf(acc[mt][0][jj] + b1[n * EDIM + f0], 0.f) * s_w2sum[f0] +
                fmaxf(acc[mt][1][jj] + b1[n * EDIM + f1], 0.f) * s_w2sum[f1];
#pragma unroll
      for (int off = 1; off < 16; off <<= 1) v += __shfl_xor(v, off);
      if (lr == 0) s_scorep[w][n] = v;
    }
  }
  __syncthreads();

  // softmax over 128 neighbors (wave 0), deterministic 8-term sums
  if (w == 0) {
    float v0 = s_b2sum[l], v1 = s_b2sum[l + 64];
#pragma unroll
    for (int ww = 0; ww < 8; ++ww) {
      v0 += s_scorep[ww][l];
      v1 += s_scorep[ww][l + 64];
    }
    float m = fmaxf(v0, v1);
#pragma unroll
    for (int off = 1; off < 64; off <<= 1) m = fmaxf(m, __shfl_xor(m, off));
    const float e0 = expf(v0 - m), e1 = expf(v1 - m);
    float s = e0 + e1;
#pragma unroll
    for (int off = 1; off < 64; off <<= 1) s += __shfl_xor(s, off);
    const float inv = 1.f / s;
    s_attn[l] = e0 * inv;
    s_attn[l + 64] = e1 * inv;
  }
  __syncthreads();

  // weighted_ent[f] = sum_n attn[n] * ent_table[tail[n]][f]
  {
    const int f = tid & 255;
    const int half = tid >> 8;
    const int nbase = half * 64;
    float a = 0.f;
#pragma unroll 8
    for (int i = 0; i < 64; ++i) {
      const int n = nbase + i;
      a += s_attn[n] * ent_table[(long)s_tail[n] * EDIM + f];
    }
    s_we[half][f] = a;
  }
  __syncthreads();

  // x = [we | d] @ lin_w  (split the 512-row contraction across the two halves)
  {
    const int f = tid & 255;
    const int half = tid >> 8;
    const float* wp = lin_w + (long)half * EDIM * EDIM + f;
    float a = 0.f;
    if (half == 0) {
#pragma unroll 16
      for (int e = 0; e < EDIM; ++e) a += (s_we[0][e] + s_we[1][e]) * wp[(long)e * EDIM];
    } else {
#pragma unroll 16
      for (int e = 0; e < EDIM; ++e) a += s_d[e] * wp[(long)e * EDIM];
    }
    s_lin[half][f] = a;
  }
  __syncthreads();

  if (tid < EDIM) {
    float x = s_lin[0][tid] + s_lin[1][tid] + lin_b[tid];
    x = fmaxf(x, 0.f);
    xT[tid * NDRUG + b] = x;  // transposed for coalesced BN reads
  }
}

__global__ __launch_bounds__(256) void bn_kernel(const float* __restrict__ xT,
                                                 const float* __restrict__ gamma,
                                                 const float* __restrict__ beta,
                                                 float* __restrict__ out) {
  const int f = blockIdx.x;
  const int t = threadIdx.x;
  const float* col = xT + f * NDRUG;
  float s = 0.f, ss = 0.f;
  for (int i = t; i < NDRUG; i += 256) {
    const float v = col[i];
    s += v;
    ss += v * v;
  }
#pragma unroll
  for (int off = 1; off < 64; off <<= 1) {
    s += __shfl_xor(s, off);
    ss += __shfl_xor(ss, off);
  }
  __shared__ float as_[4], ass_[4];
  if ((t & 63) == 0) {
    as_[t >> 6] = s;
    ass_[t >> 6] = ss;
  }
  __syncthreads();
  s = as_[0] + as_[1] + as_[2] + as_[3];
  ss = ass_[0] + ass_[1] + ass_[2] + ass_[3];
  const float mean = s * (1.f / NDRUG);
  const float var = ss * (1.f / NDRUG) - mean * mean;  // biased batch variance
  const float sc = rsqrtf(var + 1e-5f) * gamma[f];
  const float sh = beta[f] - mean * sc;
  for (int i = t; i < NDRUG; i += 256) out[i * EDIM + f] = col[i] * sc + sh;
}

__global__ void tail_kernel(const float* __restrict__ gnn1, const int* __restrict__ idx,
                            float* __restrict__ out) {
  const int total4 = NDRUG * EDIM / 4;
  const float4* s4 = (const float4*)gnn1;
  float4* d4 = (float4*)(out + NDRUG * EDIM);
  for (int i = blockIdx.x * blockDim.x + threadIdx.x; i < total4;
       i += gridDim.x * blockDim.x)
    d4[i] = s4[i];
  if (blockIdx.x == 0 && threadIdx.x == 0) out[2 * NDRUG * EDIM] = (float)idx[0];
}

extern "C" void kernel_launch(void* const* d_in, const int* in_sizes, int n_in,
                              void* d_out, int out_size, void* d_ws, size_t ws_size,
                              hipStream_t stream) {
  const float* gnn1       = (const float*)d_in[0];
  const int*   idx        = (const int*)d_in[1];
  const int*   drug_name  = (const int*)d_in[2];
  const int*   adj_tail   = (const int*)d_in[3];
  const int*   adj_rel    = (const int*)d_in[4];
  const float* drug_table = (const float*)d_in[5];
  const float* rela_table = (const float*)d_in[6];
  const float* ent_table  = (const float*)d_in[7];
  const float* W1         = (const float*)d_in[8];
  const float* b1         = (const float*)d_in[9];
  const float* W2         = (const float*)d_in[10];
  const float* b2         = (const float*)d_in[11];
  const float* lin_w      = (const float*)d_in[12];
  const float* lin_b      = (const float*)d_in[13];
  const float* bn_g       = (const float*)d_in[14];
  const float* bn_b       = (const float*)d_in[15];

  float* out = (float*)d_out;
  float* xT  = (float*)d_ws;  // [EDIM][NDRUG] f32, 866304 bytes

  gnn_main<<<NDRUG, 512, 0, stream>>>(drug_name, adj_tail, adj_rel, drug_table,
                                      rela_table, ent_table, W1, b1, W2, b2,
                                      lin_w, lin_b, xT);
  bn_kernel<<<EDIM, 256, 0, stream>>>(xT, bn_g, bn_b, out);
  tail_kernel<<<240, 256, 0, stream>>>(gnn1, idx, out);
}